// Round 1
// 1684.634 us; speedup vs baseline: 4.3196x; 4.3196x over previous
//
#include <hip/hip_runtime.h>

typedef unsigned short u16;
typedef __attribute__((ext_vector_type(4))) unsigned short u16x4;
typedef __attribute__((ext_vector_type(4))) float f32x4;

#define C_  64
#define D_  64
#define H_  128
#define W_  128
#define HW_ 16384
#define S_  1048576
#define K_  192
#define AP  128   // LDS row (bf16 elems); broadcast reads in phase B are conflict-free unpadded

__device__ __forceinline__ float bf2f(u16 u){
  union { unsigned i; float f; } v; v.i = ((unsigned)u) << 16; return v.f;
}
__device__ __forceinline__ u16 f2bf(float f){
  union { unsigned i; float f; } v; v.f = f;
  unsigned r = v.i + 0x7FFFu + ((v.i >> 16) & 1u);  // round-to-nearest-even
  return (u16)(r >> 16);
}
__device__ __forceinline__ float ldx(const float* __restrict__ x, int c, int d, int h, int w){
  if ((unsigned)d < (unsigned)D_ && (unsigned)h < (unsigned)H_ && (unsigned)w < (unsigned)W_)
    return x[(c<<20) + (d<<14) + (h<<7) + w];
  return 0.f;
}

// t_d: 3x3 over (h,w); t_h: 3x3 over (d,w); t_w: 3x3 over (d,h). 19 unique taps.
__device__ __forceinline__ void compute_tri(
    const float* __restrict__ x, int c, int d, int h, int w,
    const float* wd, const float* wh, const float* ww,
    float& td, float& th, float& tw)
{
  float A00=ldx(x,c,d,h-1,w-1), A01=ldx(x,c,d,h-1,w), A02=ldx(x,c,d,h-1,w+1);
  float A10=ldx(x,c,d,h  ,w-1), A11=ldx(x,c,d,h  ,w), A12=ldx(x,c,d,h  ,w+1);
  float A20=ldx(x,c,d,h+1,w-1), A21=ldx(x,c,d,h+1,w), A22=ldx(x,c,d,h+1,w+1);
  float B00=ldx(x,c,d-1,h,w-1), B01=ldx(x,c,d-1,h,w), B02=ldx(x,c,d-1,h,w+1);
  float B20=ldx(x,c,d+1,h,w-1), B21=ldx(x,c,d+1,h,w), B22=ldx(x,c,d+1,h,w+1);
  float C00=ldx(x,c,d-1,h-1,w), C02=ldx(x,c,d-1,h+1,w);
  float C20=ldx(x,c,d+1,h-1,w), C22=ldx(x,c,d+1,h+1,w);
  td = wd[0]*A00+wd[1]*A01+wd[2]*A02+wd[3]*A10+wd[4]*A11+wd[5]*A12+wd[6]*A20+wd[7]*A21+wd[8]*A22;
  th = wh[0]*B00+wh[1]*B01+wh[2]*B02+wh[3]*A10+wh[4]*A11+wh[5]*A12+wh[6]*B20+wh[7]*B21+wh[8]*B22;
  tw = ww[0]*C00+ww[1]*B01+ww[2]*C02+ww[3]*A01+ww[4]*A11+ww[5]*A21+ww[6]*C20+ww[7]*B21+ww[8]*C22;
}

__device__ __forceinline__ float wave_sum(float v){
  #pragma unroll
  for (int off = 32; off > 0; off >>= 1) v += __shfl_down(v, off, 64);
  return v;
}

// Pass 1: depthwise conv outputs -> per-channel sum / sumsq (192 channels). No tensor writes.
__global__ __launch_bounds__(256) void k_dw_stats(
    const float* __restrict__ x, const float* __restrict__ w_d, const float* __restrict__ w_h,
    const float* __restrict__ w_w, const float* __restrict__ b_d, const float* __restrict__ b_h,
    const float* __restrict__ b_w, float* __restrict__ stats)
{
  int d = blockIdx.x, c = blockIdx.y, t = threadIdx.x;
  float wd[9], wh[9], ww[9];
  #pragma unroll
  for (int i=0;i<9;i++){ wd[i]=w_d[c*9+i]; wh[i]=w_h[c*9+i]; ww[i]=w_w[c*9+i]; }
  float bd=b_d[c], bh=b_h[c], bw=b_w[c];
  float s0=0,q0=0,s1=0,q1=0,s2=0,q2=0;
  for (int idx=t; idx<HW_; idx+=256){
    int h = idx>>7, w = idx&127;
    float td,th,tw;
    compute_tri(x,c,d,h,w,wd,wh,ww,td,th,tw);
    td+=bd; th+=bh; tw+=bw;
    s0+=td; q0+=td*td; s1+=th; q1+=th*th; s2+=tw; q2+=tw*tw;
  }
  s0=wave_sum(s0); q0=wave_sum(q0); s1=wave_sum(s1);
  q1=wave_sum(q1); s2=wave_sum(s2); q2=wave_sum(q2);
  if ((t&63)==0){
    atomicAdd(&stats[2*c],         s0); atomicAdd(&stats[2*c+1],         q0);
    atomicAdd(&stats[2*(64+c)],    s1); atomicAdd(&stats[2*(64+c)+1],    q1);
    atomicAdd(&stats[2*(128+c)],   s2); atomicAdd(&stats[2*(128+c)+1],   q2);
  }
}

__global__ void k_finalize(const float* __restrict__ stats, float* __restrict__ mu_rs, int n){
  int i = threadIdx.x;
  if (i < n){
    const float inv = 1.f/1048576.f;
    float mu  = stats[2*i]*inv;
    float var = stats[2*i+1]*inv - mu*mu;
    mu_rs[2*i]   = mu;
    mu_rs[2*i+1] = rsqrtf(var + 1e-5f);
  }
}

// Pass 2: recompute convs (lane->w coalesced), normalize+LReLU into LDS (96-row chunks, bf16),
// 64x192 pointwise in 2 chunks, write fp32 out (float4) + accumulate out-channel stats.
// Block swizzle: XCD-chunked, (4d x 16h) tiles per XCD so halo rows are L2-resident.
__global__ __launch_bounds__(256) void k_pointwise(
    const float* __restrict__ x, const float* __restrict__ w_d, const float* __restrict__ w_h,
    const float* __restrict__ w_w, const float* __restrict__ b_d, const float* __restrict__ b_h,
    const float* __restrict__ b_w, const float* __restrict__ w_pw, const float* __restrict__ b_pw,
    const float* __restrict__ mu_rs, float* __restrict__ stats_out, float* __restrict__ out)
{
  __shared__ u16 a_lds[96*AP];        // [k_local][w] bf16 activations, one 96-row chunk
  __shared__ u16 w_lds[K_*64];        // [k][c] bf16 pointwise weights (transposed), all 192 rows
  __shared__ float cstat[128];
  int t = threadIdx.x;

  // XCD-chunked swizzle: xcd gets d in [8*xcd, 8*xcd+8), ordered as (4d x 16h) tiles.
  int bid = blockIdx.x;
  int xcd = bid & 7, j = bid >> 3;
  int tile = j >> 6, idx = j & 63;                  // 16 tiles of 64 blocks per XCD
  int d = (xcd<<3) + ((tile&1)<<2) + (idx>>4);
  int h = ((tile>>1)<<4) + (idx&15);

  for (int i=t; i<K_*64; i+=256){ int c = i & 63, k = i >> 6; w_lds[i] = f2bf(w_pw[c*K_ + k]); }
  if (t < 128) cstat[t] = 0.f;

  int lane = t & 63, wave = t >> 6;
  int c0 = (t & 15) << 2, p0 = (t >> 4) << 3;       // phase-B register tile: 4c x 8p
  float acc[4][8];
  #pragma unroll
  for (int i=0;i<4;i++){
    float b = b_pw[c0+i];
    #pragma unroll
    for (int jj=0;jj<8;jj++) acc[i][jj]=b;
  }

  for (int g=0; g<2; ++g){
    __syncthreads();  // phase-B reads of previous chunk done (also covers w_lds/cstat init)

    // phase A: channels [32g, 32g+32); each wave owns 8 channels, lane -> w (coalesced)
    for (int cc=0; cc<8; ++cc){
      int c = (g<<5) + (wave<<3) + cc;              // wave-uniform
      float wd[9], wh[9], ww[9];
      #pragma unroll
      for (int i=0;i<9;i++){ wd[i]=w_d[c*9+i]; wh[i]=w_h[c*9+i]; ww[i]=w_w[c*9+i]; }
      float bd=b_d[c], bh=b_h[c], bw=b_w[c];
      float mu0=mu_rs[2*c],       r0=mu_rs[2*c+1];
      float mu1=mu_rs[2*(64+c)],  r1=mu_rs[2*(64+c)+1];
      float mu2=mu_rs[2*(128+c)], r2=mu_rs[2*(128+c)+1];
      int rl = (wave<<3) + cc;                      // local row 0..31
      #pragma unroll
      for (int u=0; u<2; ++u){
        int w = lane + (u<<6);
        float td,th,tw;
        compute_tri(x,c,d,h,w,wd,wh,ww,td,th,tw);
        td+=bd; th+=bh; tw+=bw;
        float a0=(td-mu0)*r0; a0 = a0>=0.f ? a0 : 0.01f*a0;
        float a1=(th-mu1)*r1; a1 = a1>=0.f ? a1 : 0.01f*a1;
        float a2=(tw-mu2)*r2; a2 = a2>=0.f ? a2 : 0.01f*a2;
        a_lds[ rl     *AP + w] = f2bf(a0);
        a_lds[(32+rl) *AP + w] = f2bf(a1);
        a_lds[(64+rl) *AP + w] = f2bf(a2);
      }
    }
    __syncthreads();

    // phase B: 96 k-rows of this chunk
    for (int ci=0; ci<32; ++ci){
      #pragma unroll
      for (int s=0;s<3;s++){
        int kr = s*32 + ci;                         // a_lds row
        int kw = s*64 + (g<<5) + ci;                // w_lds row (global k)
        u16x4 wv  = *(const u16x4*)&w_lds[kw*64 + c0];
        u16x4 av0 = *(const u16x4*)&a_lds[kr*AP + p0];
        u16x4 av1 = *(const u16x4*)&a_lds[kr*AP + p0 + 4];
        float wf[4], af[8];
        #pragma unroll
        for (int i=0;i<4;i++) wf[i]=bf2f(wv[i]);
        #pragma unroll
        for (int jj=0;jj<4;jj++){ af[jj]=bf2f(av0[jj]); af[4+jj]=bf2f(av1[jj]); }
        #pragma unroll
        for (int i=0;i<4;i++)
          #pragma unroll
          for (int jj=0;jj<8;jj++) acc[i][jj] += wf[i]*af[jj];
      }
    }
  }

  int base = (d<<14) + (h<<7) + p0;
  #pragma unroll
  for (int i=0;i<4;i++){
    float s=0.f,q=0.f;
    f32x4 v0, v1;
    #pragma unroll
    for (int jj=0;jj<4;jj++){
      float a=acc[i][jj], b=acc[i][4+jj];
      v0[jj]=a; v1[jj]=b;
      s+=a+b; q+=a*a+b*b;
    }
    *(f32x4*)&out[((c0+i)<<20) + base]     = v0;
    *(f32x4*)&out[((c0+i)<<20) + base + 4] = v1;
    atomicAdd(&cstat[2*(c0+i)],   s);
    atomicAdd(&cstat[2*(c0+i)+1], q);
  }
  __syncthreads();
  if (t<128) atomicAdd(&stats_out[t], cstat[t]);
}

// Pass 3: in-place normalize + LReLU of d_out (float4 vectorized).
__global__ __launch_bounds__(256) void k_norm_out(float* __restrict__ out, const float* __restrict__ mu_rs){
  int i = blockIdx.x*256 + threadIdx.x;   // group of 4 elems
  int c = i >> 18;                         // (i*4) >> 20
  float mu = mu_rs[2*c], rs = mu_rs[2*c+1];
  f32x4 v = ((const f32x4*)out)[i];
  f32x4 r;
  #pragma unroll
  for (int j=0;j<4;j++){
    float f=(v[j]-mu)*rs;
    r[j] = f>=0.f ? f : 0.01f*f;
  }
  ((f32x4*)out)[i] = r;
}

extern "C" void kernel_launch(void* const* d_in, const int* in_sizes, int n_in,
                              void* d_out, int out_size, void* d_ws, size_t ws_size,
                              hipStream_t stream){
  const float* x    = (const float*)d_in[0];
  const float* w_d  = (const float*)d_in[1];
  const float* b_d  = (const float*)d_in[2];
  const float* w_h  = (const float*)d_in[3];
  const float* b_h  = (const float*)d_in[4];
  const float* w_w  = (const float*)d_in[5];
  const float* b_w  = (const float*)d_in[6];
  const float* w_pw = (const float*)d_in[7];
  const float* b_pw = (const float*)d_in[8];
  float* out = (float*)d_out;
  float* ws = (float*)d_ws;
  float* stats_dw  = ws;        // 384 floats
  float* mu_rs_dw  = ws + 384;  // 384 floats
  float* stats_out = ws + 768;  // 128 floats
  float* mu_rs_out = ws + 896;  // 128 floats

  hipMemsetAsync(d_ws, 0, 4096, stream);
  k_dw_stats<<<dim3(D_, C_), 256, 0, stream>>>(x, w_d, w_h, w_w, b_d, b_h, b_w, stats_dw);
  k_finalize<<<1, 256, 0, stream>>>(stats_dw, mu_rs_dw, 192);
  k_pointwise<<<D_*H_, 256, 0, stream>>>(x, w_d, w_h, w_w, b_d, b_h, b_w, w_pw, b_pw,
                                         mu_rs_dw, stats_out, out);
  k_finalize<<<1, 256, 0, stream>>>(stats_out, mu_rs_out, 64);
  k_norm_out<<<(S_/4)*C_/256, 256, 0, stream>>>(out, mu_rs_out);
}